// Round 3
// baseline (10364.760 us; speedup 1.0000x reference)
//
#include <hip/hip_runtime.h>
#include <hip/hip_cooperative_groups.h>
#include <math.h>

namespace cg = cooperative_groups;

#define BB 32
#define EE 256
#define HH 512
#define VV 32000
#define TT 64
#define GO_ID 2
#define EOS_ID 3

// ======================= cooperative fused path =======================
#define CNB 250
#define CNT 1024

// out layout (floats)
#define OUT_WO   65536000ULL
#define OUT_EMB  (OUT_WO + 2048ULL)
#define OUT_LEN  (OUT_EMB + 524288ULL)

__device__ __forceinline__ void merge_sm(float& m, float& s, float& av, int& ai,
                                         float m2, float s2, float av2, int ai2)
{
    float mn = fmaxf(m, m2);
    s = s*expf(m - mn) + s2*expf(m2 - mn);
    m = mn;
    if (av2 > av || (av2 == av && ai2 < ai)) { av = av2; ai = ai2; }
}

struct SmemT {
    float  logitS[32*129];   // 16.5 KB  (L phase: 32 batch x 128 rows, +1 pad)
    float4 redS[CNT];        // 16 KB    (block-level softmax/argmax partials)
    float  gruS[CNT*6];      // 24 KB    (GRU partial sums)
    float  mprev[32];
    float  sprev[32];
    int    toksS[32];
    int    flagsS;
};

__device__ __forceinline__ void gru_phase(
    int bk, int tid, bool init, const int* toks,
    const float* __restrict__ emb,
    const float* __restrict__ Wih, const float* __restrict__ bih,
    const float* __restrict__ Whh, const float* __restrict__ bhh,
    const float* __restrict__ h0, const float* __restrict__ hprevT,
    float* __restrict__ hTout, float* __restrict__ gruS)
{
    const int b   = tid & 31;
    const int q   = tid >> 5;     // 0..31
    const int ko  = q & 3;
    const int seg = q >> 2;       // 0..7  (dot split into 8 segments)
    const int k   = bk*4 + ko;
    const int tok = init ? GO_ID : toks[b];

    float s_ir = 0.f, s_iz = 0.f, s_in = 0.f;
    {
        const float4* x4 = (const float4*)emb + (size_t)tok*64;
        const float4* wr = (const float4*)Wih + (size_t)k*64;
        const float4* wz = (const float4*)Wih + (size_t)(HH + k)*64;
        const float4* wn = (const float4*)Wih + (size_t)(2*HH + k)*64;
        #pragma unroll
        for (int i = 0; i < 8; ++i) {
            int c = seg*8 + i;
            float4 xv = x4[c];
            float4 a  = wr[c]; s_ir += a.x*xv.x + a.y*xv.y + a.z*xv.z + a.w*xv.w;
            float4 bz = wz[c]; s_iz += bz.x*xv.x + bz.y*xv.y + bz.z*xv.z + bz.w*xv.w;
            float4 cn = wn[c]; s_in += cn.x*xv.x + cn.y*xv.y + cn.z*xv.z + cn.w*xv.w;
        }
    }
    float s_hr = 0.f, s_hz = 0.f, s_hn = 0.f;
    {
        const float4* wr = (const float4*)Whh + (size_t)k*128;
        const float4* wz = (const float4*)Whh + (size_t)(HH + k)*128;
        const float4* wn = (const float4*)Whh + (size_t)(2*HH + k)*128;
        const float4* h4 = init ? ((const float4*)h0 + b*128) : ((const float4*)hprevT);
        #pragma unroll
        for (int i = 0; i < 16; ++i) {
            int c = seg*16 + i;
            float4 hv = init ? h4[c] : h4[c*32 + b];
            float4 a  = wr[c]; s_hr += a.x*hv.x + a.y*hv.y + a.z*hv.z + a.w*hv.w;
            float4 bz = wz[c]; s_hz += bz.x*hv.x + bz.y*hv.y + bz.z*hv.z + bz.w*hv.w;
            float4 cn = wn[c]; s_hn += cn.x*hv.x + cn.y*hv.y + cn.z*hv.z + cn.w*hv.w;
        }
    }
    const int si = (q*32 + b)*6;
    gruS[si+0] = s_ir; gruS[si+1] = s_iz; gruS[si+2] = s_in;
    gruS[si+3] = s_hr; gruS[si+4] = s_hz; gruS[si+5] = s_hn;
    __syncthreads();
    if (q < 4) {
        const int kk = bk*4 + q;
        float ir = bih[kk], iz = bih[HH+kk], inn = bih[2*HH+kk];
        float hr = bhh[kk], hz = bhh[HH+kk], hn  = bhh[2*HH+kk];
        #pragma unroll
        for (int s2 = 0; s2 < 8; ++s2) {
            int base = ((s2*4 + q)*32 + b)*6;
            ir  += gruS[base+0]; iz += gruS[base+1]; inn += gruS[base+2];
            hr  += gruS[base+3]; hz += gruS[base+4]; hn  += gruS[base+5];
        }
        float r = 1.f/(1.f + expf(-(ir + hr)));
        float z = 1.f/(1.f + expf(-(iz + hz)));
        float n = tanhf(inn + r*hn);
        float hp = init ? h0[b*HH + kk] : hprevT[(kk>>2)*128 + b*4 + (kk&3)];
        hTout[(kk>>2)*128 + b*4 + (kk&3)] = (1.f - z)*n + z*hp;
    }
}

__global__ __launch_bounds__(CNT, 4)
void fused_decoder(const float* __restrict__ emb,
                   const float* __restrict__ Wih, const float* __restrict__ bih,
                   const float* __restrict__ Whh, const float* __restrict__ bhh,
                   const float* __restrict__ Wout, const float* __restrict__ bout,
                   const float* __restrict__ h0,
                   float* __restrict__ out, float* __restrict__ ws)
{
    cg::grid_group grid = cg::this_grid();
    const int blk = blockIdx.x, tid = threadIdx.x;

    float* hb0 = ws;
    float* hb1 = ws + 16384;
    float4* part4 = (float4*)(ws + 32768);   // [250][32] float4

    float* w_pro  = out;
    float* w_o    = out + OUT_WO;
    float* emb_sq = out + OUT_EMB;
    float* len_o  = out + OUT_LEN;

    __shared__ SmemT sm;

    int len_b = 0;
    if (tid == 0) sm.flagsS = 0;
    __syncthreads();

    // h(0) = GRU(emb[GO], h0)  -> hb0
    if (blk >= 64 && blk < 192)
        gru_phase(blk-64, tid, true, sm.toksS, emb, Wih, bih, Whh, bhh, h0, nullptr, hb0, sm.gruS);
    grid.sync();

    for (int t = 0; t < TT; ++t) {
        const float* hT = (t & 1) ? hb1 : hb0;

        // ---- Phase L: normalize w_pro(t-1), logits(t), block partials
        if (t > 0) {
            const int vl = tid & 127, bq = tid >> 7;
            float* wp = w_pro + (size_t)(t-1)*1024000 + (size_t)blk*128;
            #pragma unroll
            for (int rr = 0; rr < 4; ++rr) {
                int b2 = rr*8 + bq;
                size_t idx = (size_t)b2*VV + vl;
                wp[idx] = expf(wp[idx] - sm.mprev[b2]) * sm.sprev[b2];
            }
        }
        {
            const int b = tid & 31, vg = tid >> 5;      // vg 0..31, 4 rows each
            const int v0 = blk*128 + vg*4;
            float a0=0.f, a1=0.f, a2=0.f, a3=0.f;
            const float4* hT4 = (const float4*)hT;
            const float4* w0 = (const float4*)Wout + (size_t)v0*128;
            const float4* w1 = w0 + 128;
            const float4* w2 = w0 + 256;
            const float4* w3 = w0 + 384;
            for (int c4 = 0; c4 < 128; ++c4) {
                float4 hv = hT4[c4*32 + b];
                float4 p;
                p = w0[c4]; a0 += p.x*hv.x + p.y*hv.y + p.z*hv.z + p.w*hv.w;
                p = w1[c4]; a1 += p.x*hv.x + p.y*hv.y + p.z*hv.z + p.w*hv.w;
                p = w2[c4]; a2 += p.x*hv.x + p.y*hv.y + p.z*hv.z + p.w*hv.w;
                p = w3[c4]; a3 += p.x*hv.x + p.y*hv.y + p.z*hv.z + p.w*hv.w;
            }
            sm.logitS[b*129 + vg*4 + 0] = a0 + bout[v0+0];
            sm.logitS[b*129 + vg*4 + 1] = a1 + bout[v0+1];
            sm.logitS[b*129 + vg*4 + 2] = a2 + bout[v0+2];
            sm.logitS[b*129 + vg*4 + 3] = a3 + bout[v0+3];
        }
        __syncthreads();
        {   // coalesced raw-logit store
            const int vl = tid & 127, bq = tid >> 7;
            float* wp = w_pro + (size_t)t*1024000 + (size_t)blk*128;
            #pragma unroll
            for (int rr = 0; rr < 4; ++rr) {
                int b2 = rr*8 + bq;
                wp[(size_t)b2*VV + vl] = sm.logitS[b2*129 + vl];
            }
        }
        {   // per-thread partial over 4 rows
            const int b = tid & 31, l = tid >> 5;
            float m=-INFINITY, s=0.f, av=-INFINITY; int ai=0;
            #pragma unroll
            for (int i = 0; i < 4; ++i) {
                int j = l + (i<<5);
                float val = sm.logitS[b*129 + j];
                if (val > m) { s = s*expf(m - val) + 1.f; m = val; }
                else         { s += expf(val - m); }
                int vglob = blk*128 + j;
                if (vglob >= 2 && val > av) { av = val; ai = vglob; }
            }
            sm.redS[tid] = make_float4(m, s, av, __int_as_float(ai));
        }
        __syncthreads();
        if (tid < 32) {
            float4 p0 = sm.redS[tid];
            float m=p0.x, s=p0.y, av=p0.z; int ai=__float_as_int(p0.w);
            for (int jj = 1; jj < 32; ++jj) {
                float4 p = sm.redS[tid + (jj<<5)];
                merge_sm(m, s, av, ai, p.x, p.y, p.z, __float_as_int(p.w));
            }
            part4[blk*32 + tid] = make_float4(m, s, av, __int_as_float(ai));
        }
        grid.sync();

        // ---- Phase RG: every block reduces all partials -> tokens; outputs; GRU
        {
            const int b = tid & 31, jg = tid >> 5;
            float m=-INFINITY, s=0.f, av=-INFINITY; int ai=0;
            #pragma unroll
            for (int i = 0; i < 8; ++i) {
                int j = jg + (i<<5);
                if (j < CNB) {
                    float4 p = part4[j*32 + b];
                    merge_sm(m, s, av, ai, p.x, p.y, p.z, __float_as_int(p.w));
                }
            }
            sm.redS[tid] = make_float4(m, s, av, __int_as_float(ai));
        }
        __syncthreads();
        if (tid < 32) {
            float4 p0 = sm.redS[tid];
            float m=p0.x, s=p0.y, av=p0.z; int ai=__float_as_int(p0.w);
            for (int jj = 1; jj < 32; ++jj) {
                float4 p = sm.redS[tid + (jj<<5)];
                merge_sm(m, s, av, ai, p.x, p.y, p.z, __float_as_int(p.w));
            }
            sm.mprev[tid] = m;
            sm.sprev[tid] = 1.f/s;
            sm.toksS[tid] = ai;
        }
        __syncthreads();
        const int oldflags = sm.flagsS;
        __syncthreads();
        {
            unsigned long long bal = __ballot((tid < 32) && (sm.toksS[tid & 31] == EOS_ID));
            if (tid == 0) sm.flagsS = oldflags | (int)(bal & 0xFFFFFFFFull);
        }
        if (blk < 32) {
            const int tok   = sm.toksS[blk];
            const int alive = ((oldflags >> blk) & 1) ^ 1;
            if (tid == 0) w_o[t*BB + blk] = alive ? (float)tok : 0.f;
            len_b += alive;
            if (tid < EE) {
                float e = alive ? emb[(size_t)tok*EE + tid] : 0.f;
                emb_sq[(size_t)t*8192 + blk*EE + tid] = e;
            }
            if (t == TT-1 && tid == 32) len_o[blk] = (float)len_b;
        }
        if (t < TT-1 && blk >= 64 && blk < 192)
            gru_phase(blk-64, tid, false, sm.toksS, emb, Wih, bih, Whh, bhh, h0,
                      (t & 1) ? hb1 : hb0, (t & 1) ? hb0 : hb1, sm.gruS);
        grid.sync();
    }

    // ---- final normalize for t = 63
    {
        const int vl = tid & 127, bq = tid >> 7;
        float* wp = w_pro + (size_t)(TT-1)*1024000 + (size_t)blk*128;
        #pragma unroll
        for (int rr = 0; rr < 4; ++rr) {
            int b2 = rr*8 + bq;
            size_t idx = (size_t)b2*VV + vl;
            wp[idx] = expf(wp[idx] - sm.mprev[b2]) * sm.sprev[b2];
        }
    }
}

// ======================= fallback multi-launch path (round-2, proven) =======================
#define NBL 500
#define NT  256
#define WS_HT0   0
#define WS_HT1   16384
#define WS_X     32768
#define WS_PART  40960
#define WS_M     104960
#define WS_SINV  104992
#define WS_INT   105024

__global__ __launch_bounds__(NT)
void k_init(const float* __restrict__ emb, float* __restrict__ ws)
{
    float* xbuf = ws + WS_X;
    int* toki  = (int*)(ws + WS_INT);
    int* flags = toki;
    int* lenac = toki + 32;
    xbuf[blockIdx.x*EE + threadIdx.x] = emb[GO_ID*EE + threadIdx.x];
    if (blockIdx.x == 0 && threadIdx.x < BB) { flags[threadIdx.x] = 0; lenac[threadIdx.x] = 0; }
}

__global__ __launch_bounds__(NT)
void k_gru(const float* __restrict__ Wih, const float* __restrict__ bih,
           const float* __restrict__ Whh, const float* __restrict__ bhh,
           const float* __restrict__ h0, float* __restrict__ ws, int t)
{
    const int blk = blockIdx.x, tid = threadIdx.x;
    float* hTprev = ws + (((t & 1) == 0) ? WS_HT1 : WS_HT0);
    float* hTcur  = ws + (((t & 1) == 0) ? WS_HT0 : WS_HT1);
    const float* xbuf = ws + WS_X;

    __shared__ float smem[1536];

    const int b    = tid & 31;
    const int q    = tid >> 5;
    const int k    = blk*4 + (q & 3);
    const int half = q >> 2;

    float s_ir = 0.f, s_iz = 0.f, s_in = 0.f;
    {
        const float4* x4 = (const float4*)xbuf + b*64;
        const float4* wr = (const float4*)Wih + (size_t)k*64;
        const float4* wz = (const float4*)Wih + (size_t)(HH + k)*64;
        const float4* wn = (const float4*)Wih + (size_t)(2*HH + k)*64;
        const int c0 = half*32, c1 = c0 + 32;
        for (int c4 = c0; c4 < c1; ++c4) {
            float4 xv = x4[c4];
            float4 a  = wr[c4]; s_ir += a.x*xv.x + a.y*xv.y + a.z*xv.z + a.w*xv.w;
            float4 bz = wz[c4]; s_iz += bz.x*xv.x + bz.y*xv.y + bz.z*xv.z + bz.w*xv.w;
            float4 cn = wn[c4]; s_in += cn.x*xv.x + cn.y*xv.y + cn.z*xv.z + cn.w*xv.w;
        }
    }
    float s_hr = 0.f, s_hz = 0.f, s_hn = 0.f;
    {
        const float4* wr = (const float4*)Whh + (size_t)k*128;
        const float4* wz = (const float4*)Whh + (size_t)(HH + k)*128;
        const float4* wn = (const float4*)Whh + (size_t)(2*HH + k)*128;
        const int c0 = half*64, c1 = c0 + 64;
        if (t == 0) {
            const float4* h4 = (const float4*)h0 + b*128;
            for (int c4 = c0; c4 < c1; ++c4) {
                float4 hv = h4[c4];
                float4 a  = wr[c4]; s_hr += a.x*hv.x + a.y*hv.y + a.z*hv.z + a.w*hv.w;
                float4 bz = wz[c4]; s_hz += bz.x*hv.x + bz.y*hv.y + bz.z*hv.z + bz.w*hv.w;
                float4 cn = wn[c4]; s_hn += cn.x*hv.x + cn.y*hv.y + cn.z*hv.z + cn.w*hv.w;
            }
        } else {
            const float4* h4 = (const float4*)hTprev;
            for (int c4 = c0; c4 < c1; ++c4) {
                float4 hv = h4[c4*32 + b];
                float4 a  = wr[c4]; s_hr += a.x*hv.x + a.y*hv.y + a.z*hv.z + a.w*hv.w;
                float4 bz = wz[c4]; s_hz += bz.x*hv.x + bz.y*hv.y + bz.z*hv.z + bz.w*hv.w;
                float4 cn = wn[c4]; s_hn += cn.x*hv.x + cn.y*hv.y + cn.z*hv.z + cn.w*hv.w;
            }
        }
    }
    const int si = (q*32 + b)*6;
    smem[si+0] = s_ir; smem[si+1] = s_iz; smem[si+2] = s_in;
    smem[si+3] = s_hr; smem[si+4] = s_hz; smem[si+5] = s_hn;
    __syncthreads();
    if (q < 4) {
        const int i0 = (q*32 + b)*6, i1 = ((q+4)*32 + b)*6;
        float ir  = smem[i0+0] + smem[i1+0] + bih[k];
        float iz  = smem[i0+1] + smem[i1+1] + bih[HH + k];
        float inn = smem[i0+2] + smem[i1+2] + bih[2*HH + k];
        float hr  = smem[i0+3] + smem[i1+3] + bhh[k];
        float hz  = smem[i0+4] + smem[i1+4] + bhh[HH + k];
        float hn  = smem[i0+5] + smem[i1+5] + bhh[2*HH + k];
        float r = 1.f/(1.f + expf(-(ir + hr)));
        float z = 1.f/(1.f + expf(-(iz + hz)));
        float n = tanhf(inn + r*hn);
        float hp = (t == 0) ? h0[b*HH + k] : hTprev[(k>>2)*128 + b*4 + (k&3)];
        float hv = (1.f - z)*n + z*hp;
        hTcur[(k>>2)*128 + b*4 + (k&3)] = hv;
    }
}

__global__ __launch_bounds__(NT)
void k_logits(const float* __restrict__ Wout, const float* __restrict__ bout,
              float* __restrict__ out, float* __restrict__ ws, int t)
{
    const int blk = blockIdx.x, tid = threadIdx.x;
    const float* hTcur = ws + (((t & 1) == 0) ? WS_HT0 : WS_HT1);
    float* part  = ws + WS_PART;
    const float* Mrow  = ws + WS_M;
    const float* SinvA = ws + WS_SINV;
    float* w_pro = out;

    __shared__ float smem[2080];

    if (t > 0) {
        float* wp = w_pro + (size_t)(t-1)*1024000 + blk*64;
        const int vl = tid & 63, bq = tid >> 6;
        #pragma unroll
        for (int r = 0; r < 8; ++r) {
            int b = r*4 + bq;
            size_t idx = (size_t)b*VV + vl;
            wp[idx] = expf(wp[idx] - Mrow[b]) * SinvA[b];
        }
    }

    const int b  = tid & 31;
    const int vg = tid >> 5;
    const int v0 = blk*64 + vg*8;
    float acc[8] = {0.f,0.f,0.f,0.f,0.f,0.f,0.f,0.f};
    const float4* hT4  = (const float4*)hTcur;
    const float4* wrow = (const float4*)Wout + (size_t)v0*128;
    for (int c4 = 0; c4 < 128; ++c4) {
        float4 hv = hT4[c4*32 + b];
        #pragma unroll
        for (int i = 0; i < 8; ++i) {
            float4 wv = wrow[(size_t)i*128 + c4];
            acc[i] += wv.x*hv.x + wv.y*hv.y + wv.z*hv.z + wv.w*hv.w;
        }
    }
    __syncthreads();
    #pragma unroll
    for (int i = 0; i < 8; ++i)
        smem[b*65 + vg*8 + i] = acc[i] + bout[v0 + i];
    __syncthreads();
    {
        float* wp = w_pro + (size_t)t*1024000 + blk*64;
        const int vl = tid & 63, bq = tid >> 6;
        #pragma unroll
        for (int r = 0; r < 8; ++r) {
            int b2 = r*4 + bq;
            wp[(size_t)b2*VV + vl] = smem[b2*65 + vl];
        }
    }
    {
        const int rb = tid >> 3, l = tid & 7;
        float m = -INFINITY, s = 0.f, av = -INFINITY; int ai = 0;
        for (int j = l; j < 64; j += 8) {
            float val = smem[rb*65 + j];
            if (val > m) { s = s*expf(m - val) + 1.f; m = val; }
            else         { s += expf(val - m); }
            int vglob = blk*64 + j;
            if (vglob >= 2 && val > av) { av = val; ai = vglob; }
        }
        for (int d = 1; d < 8; d <<= 1) {
            float m2  = __shfl_xor(m, d);
            float s2  = __shfl_xor(s, d);
            float av2 = __shfl_xor(av, d);
            int   ai2 = __shfl_xor(ai, d);
            float mn = fmaxf(m, m2);
            s = s*expf(m - mn) + s2*expf(m2 - mn); m = mn;
            if (av2 > av || (av2 == av && ai2 < ai)) { av = av2; ai = ai2; }
        }
        if (l == 0)
            ((float4*)part)[blk*32 + rb] = make_float4(m, s, av, __int_as_float(ai));
    }
}

__global__ __launch_bounds__(NT)
void k_reduce(const float* __restrict__ emb, float* __restrict__ out,
              float* __restrict__ ws, int t)
{
    const int b = blockIdx.x, tid = threadIdx.x;
    const float* part = ws + WS_PART;
    float* Mrow  = ws + WS_M;
    float* SinvA = ws + WS_SINV;
    int*   flags = (int*)(ws + WS_INT);
    int*   lenac = flags + 32;
    float* xbuf  = ws + WS_X;

    float* w_o    = out + OUT_WO;
    float* emb_sq = out + OUT_EMB;
    float* len_o  = out + OUT_LEN;

    __shared__ float smem[32];

    float m = -INFINITY, s = 0.f, av = -INFINITY; int ai = 0;
    for (int j = tid; j < NBL; j += NT) {
        float4 p = ((const float4*)part)[j*32 + b];
        float mn = fmaxf(m, p.x);
        s = s*expf(m - mn) + p.y*expf(p.x - mn); m = mn;
        int aij = __float_as_int(p.w);
        if (p.z > av || (p.z == av && aij < ai)) { av = p.z; ai = aij; }
    }
    for (int d = 1; d < 64; d <<= 1) {
        float m2  = __shfl_xor(m, d);
        float s2  = __shfl_xor(s, d);
        float av2 = __shfl_xor(av, d);
        int   ai2 = __shfl_xor(ai, d);
        float mn = fmaxf(m, m2);
        s = s*expf(m - mn) + s2*expf(m2 - mn); m = mn;
        if (av2 > av || (av2 == av && ai2 < ai)) { av = av2; ai = ai2; }
    }
    const int wid = tid >> 6, lane = tid & 63;
    if (lane == 0) {
        smem[wid*4+0] = m; smem[wid*4+1] = s;
        smem[wid*4+2] = av; smem[wid*4+3] = __int_as_float(ai);
    }
    __syncthreads();
    if (tid == 0) {
        float M = smem[0], S = smem[1], AV = smem[2];
        int AI = __float_as_int(smem[3]);
        for (int w2 = 1; w2 < 4; ++w2) {
            float m2 = smem[w2*4], s2 = smem[w2*4+1], av2 = smem[w2*4+2];
            int ai2 = __float_as_int(smem[w2*4+3]);
            float mn = fmaxf(M, m2);
            S = S*expf(M - mn) + s2*expf(m2 - mn); M = mn;
            if (av2 > AV || (av2 == AV && ai2 < AI)) { AV = av2; AI = ai2; }
        }
        Mrow[b] = M; SinvA[b] = 1.f/S;
        int fl = flags[b];
        int alive = fl ? 0 : 1;
        w_o[t*BB + b] = alive ? (float)AI : 0.f;
        flags[b] = fl | (AI == EOS_ID ? 1 : 0);
        lenac[b] += alive;
        if (t == TT-1) len_o[b] = (float)lenac[b];
        smem[16] = __int_as_float(AI);
        smem[17] = (float)alive;
    }
    __syncthreads();
    const int tok = __float_as_int(smem[16]);
    const float alive = smem[17];
    float e = emb[(size_t)tok*EE + tid];
    xbuf[b*EE + tid] = e;
    emb_sq[(size_t)t*8192 + b*EE + tid] = alive * e;
}

__global__ __launch_bounds__(NT)
void k_norm_last(float* __restrict__ out, float* __restrict__ ws)
{
    const int blk = blockIdx.x, tid = threadIdx.x;
    const float* Mrow  = ws + WS_M;
    const float* SinvA = ws + WS_SINV;
    float* wp = out + (size_t)(TT-1)*1024000 + blk*64;
    const int vl = tid & 63, bq = tid >> 6;
    #pragma unroll
    for (int r = 0; r < 8; ++r) {
        int b = r*4 + bq;
        size_t idx = (size_t)b*VV + vl;
        wp[idx] = expf(wp[idx] - Mrow[b]) * SinvA[b];
    }
}

extern "C" void kernel_launch(void* const* d_in, const int* in_sizes, int n_in,
                              void* d_out, int out_size, void* d_ws, size_t ws_size,
                              hipStream_t stream)
{
    const float* emb  = (const float*)d_in[0];
    const float* Wih  = (const float*)d_in[1];
    const float* bih  = (const float*)d_in[2];
    const float* Whh  = (const float*)d_in[3];
    const float* bhh  = (const float*)d_in[4];
    const float* Wout = (const float*)d_in[5];
    const float* bout = (const float*)d_in[6];
    const float* h0   = (const float*)d_in[7];
    float* out = (float*)d_out;
    float* ws  = (float*)d_ws;

    void* args[] = { (void*)&emb, (void*)&Wih, (void*)&bih, (void*)&Whh, (void*)&bhh,
                     (void*)&Wout, (void*)&bout, (void*)&h0, (void*)&out, (void*)&ws };
    hipError_t err = hipLaunchCooperativeKernel((const void*)fused_decoder,
                                                dim3(CNB), dim3(CNT), args, 0, stream);
    if (err != hipSuccess) {
        (void)hipGetLastError();   // clear sticky error; use proven multi-launch path
        hipLaunchKernelGGL(k_init, dim3(BB), dim3(NT), 0, stream, emb, ws);
        for (int t = 0; t < TT; ++t) {
            hipLaunchKernelGGL(k_gru,    dim3(128), dim3(NT), 0, stream, Wih, bih, Whh, bhh, h0, ws, t);
            hipLaunchKernelGGL(k_logits, dim3(NBL), dim3(NT), 0, stream, Wout, bout, out, ws, t);
            hipLaunchKernelGGL(k_reduce, dim3(BB),  dim3(NT), 0, stream, emb, out, ws, t);
        }
        hipLaunchKernelGGL(k_norm_last, dim3(NBL), dim3(NT), 0, stream, out, ws);
    }
}

// Round 4
// 9639.738 us; speedup vs baseline: 1.0752x; 1.0752x over previous
//
#include <hip/hip_runtime.h>
#include <hip/hip_cooperative_groups.h>
#include <math.h>

namespace cg = cooperative_groups;

#define BB 32
#define EE 256
#define HH 512
#define VV 32000
#define TT 64
#define GO_ID 2
#define EOS_ID 3

// ======================= cooperative fused path =======================
#define CNB 250
#define CNT 512
#define RPB 128            // W rows per block per step
#define NCH 16             // k-chunks (32 floats = 8 float4 each)
#define WROW 9             // float4 stride per row in LDS tile (8 + 1 pad)

// out layout (floats)
#define OUT_WO   65536000ULL
#define OUT_EMB  (OUT_WO + 2048ULL)
#define OUT_LEN  (OUT_EMB + 524288ULL)

__device__ __forceinline__ void merge_sm(float& m, float& s, float& av, int& ai,
                                         float m2, float s2, float av2, int ai2)
{
    float mn = fmaxf(m, m2);
    s = s*expf(m - mn) + s2*expf(m2 - mn);
    m = mn;
    if (av2 > av || (av2 == av && ai2 < ai)) { av = av2; ai = ai2; }
}

struct SmemT {
    float4 wbuf[2][RPB*WROW];   // 36864 B : W tile double buffer
    float4 redSm[1024];         // 16384 B : [b][rslot] partials; alias: gruS (12 KB)
    float  mprev[32];
    float  sprev[32];
    int    toksS[32];
    int    flagsS;
};

// GRU phase for 512-thread blocks; block bk handles k rows bk*4..bk*4+3
__device__ __forceinline__ void gru_phase(
    int bk, int tid, bool init, const int* toks,
    const float* __restrict__ emb,
    const float* __restrict__ Wih, const float* __restrict__ bih,
    const float* __restrict__ Whh, const float* __restrict__ bhh,
    const float* __restrict__ h0, const float* __restrict__ hprevT,
    float* __restrict__ hTout, float* __restrict__ gruS)
{
    const int b   = tid & 31;
    const int q   = tid >> 5;     // 0..15
    const int ko  = q & 3;
    const int seg = q >> 2;       // 0..3
    const int k   = bk*4 + ko;
    const int tok = init ? GO_ID : toks[b];

    float s_ir = 0.f, s_iz = 0.f, s_in = 0.f;
    {
        const float4* x4 = (const float4*)emb + (size_t)tok*64;
        const float4* wr = (const float4*)Wih + (size_t)k*64;
        const float4* wz = (const float4*)Wih + (size_t)(HH + k)*64;
        const float4* wn = (const float4*)Wih + (size_t)(2*HH + k)*64;
        #pragma unroll
        for (int i = 0; i < 16; ++i) {
            int c = seg*16 + i;
            float4 xv = x4[c];
            float4 a  = wr[c]; s_ir += a.x*xv.x + a.y*xv.y + a.z*xv.z + a.w*xv.w;
            float4 bz = wz[c]; s_iz += bz.x*xv.x + bz.y*xv.y + bz.z*xv.z + bz.w*xv.w;
            float4 cn = wn[c]; s_in += cn.x*xv.x + cn.y*xv.y + cn.z*xv.z + cn.w*xv.w;
        }
    }
    float s_hr = 0.f, s_hz = 0.f, s_hn = 0.f;
    {
        const float4* wr = (const float4*)Whh + (size_t)k*128;
        const float4* wz = (const float4*)Whh + (size_t)(HH + k)*128;
        const float4* wn = (const float4*)Whh + (size_t)(2*HH + k)*128;
        const float4* h4 = init ? ((const float4*)h0 + b*128) : ((const float4*)hprevT);
        #pragma unroll
        for (int i = 0; i < 32; ++i) {
            int c = seg*32 + i;
            float4 hv = init ? h4[c] : h4[c*32 + b];
            float4 a  = wr[c]; s_hr += a.x*hv.x + a.y*hv.y + a.z*hv.z + a.w*hv.w;
            float4 bz = wz[c]; s_hz += bz.x*hv.x + bz.y*hv.y + bz.z*hv.z + bz.w*hv.w;
            float4 cn = wn[c]; s_hn += cn.x*hv.x + cn.y*hv.y + cn.z*hv.z + cn.w*hv.w;
        }
    }
    const int si = (q*32 + b)*6;
    gruS[si+0] = s_ir; gruS[si+1] = s_iz; gruS[si+2] = s_in;
    gruS[si+3] = s_hr; gruS[si+4] = s_hz; gruS[si+5] = s_hn;
    __syncthreads();
    if (q < 4) {
        const int kk = bk*4 + q;
        float ir = bih[kk], iz = bih[HH + kk], inn = bih[2*HH + kk];
        float hr = bhh[kk], hz = bhh[HH + kk], hn  = bhh[2*HH + kk];
        #pragma unroll
        for (int s2 = 0; s2 < 4; ++s2) {
            int base = ((s2*4 + q)*32 + b)*6;
            ir += gruS[base+0]; iz += gruS[base+1]; inn += gruS[base+2];
            hr += gruS[base+3]; hz += gruS[base+4]; hn  += gruS[base+5];
        }
        float r = 1.f/(1.f + expf(-(ir + hr)));
        float z = 1.f/(1.f + expf(-(iz + hz)));
        float n = tanhf(inn + r*hn);
        float hp = init ? h0[b*HH + kk] : hprevT[(kk>>2)*128 + b*4 + (kk&3)];
        hTout[(kk>>2)*128 + b*4 + (kk&3)] = (1.f - z)*n + z*hp;
    }
}

__global__ __launch_bounds__(CNT)
void fused_decoder(const float* __restrict__ emb,
                   const float* __restrict__ Wih, const float* __restrict__ bih,
                   const float* __restrict__ Whh, const float* __restrict__ bhh,
                   const float* __restrict__ Wout, const float* __restrict__ bout,
                   const float* __restrict__ h0,
                   float* __restrict__ out, float* __restrict__ ws)
{
    cg::grid_group grid = cg::this_grid();
    const int blk = blockIdx.x, tid = threadIdx.x;

    float* hb0 = ws;
    float* hb1 = ws + 16384;
    float4* part4 = (float4*)(ws + 32768);   // [250][32] float4

    float* w_pro  = out;
    float* w_o    = out + OUT_WO;
    float* emb_sq = out + OUT_EMB;
    float* len_o  = out + OUT_LEN;

    __shared__ SmemT sm;
    float* gruS = (float*)sm.redSm;          // alias (phases don't overlap)

    int len_b = 0;
    if (tid == 0) sm.flagsS = 0;
    __syncthreads();

    // h(0) = GRU(emb[GO], h0) -> hb0
    if (blk >= 64 && blk < 192)
        gru_phase(blk-64, tid, true, sm.toksS, emb, Wih, bih, Whh, bhh, h0, nullptr, hb0, gruS);
    grid.sync();

    const int bgrp  = tid & 15;        // 16 batch-pairs
    const int rslot = tid >> 4;        // 0..31 row groups (4 rows each)
    const int b0    = bgrp*2;
    const int v0    = blk*RPB;
    const float4* W4 = (const float4*)Wout;

    for (int t = 0; t < TT; ++t) {
        const float* hT = (t & 1) ? hb1 : hb0;
        const float4* hT4 = (const float4*)hT;

        // ================= Phase L =================
        // issue chunk-0 staging loads first (fly under the normalize pass)
        float4 st0[2];
        {
            #pragma unroll
            for (int i = 0; i < 2; ++i) {
                int off = i*512 + tid;            // 0..1023
                int r = off >> 3, k4 = off & 7;
                st0[i] = W4[(size_t)(v0 + r)*128 + k4];
            }
        }
        if (t > 0) {   // normalize w_pro(t-1) for this block's columns
            const int vl = tid & 127, bq = tid >> 7;
            float* wp = w_pro + (size_t)(t-1)*1024000 + (size_t)blk*128;
            #pragma unroll
            for (int rr = 0; rr < 8; ++rr) {
                int b2 = rr*4 + bq;
                size_t idx = (size_t)b2*VV + vl;
                wp[idx] = expf(wp[idx] - sm.mprev[b2]) * sm.sprev[b2];
            }
        }
        {
            #pragma unroll
            for (int i = 0; i < 2; ++i) {
                int off = i*512 + tid;
                int r = off >> 3, k4 = off & 7;
                sm.wbuf[0][r*WROW + k4] = st0[i];
            }
        }
        __syncthreads();

        float acc0[4] = {0.f,0.f,0.f,0.f};
        float acc1[4] = {0.f,0.f,0.f,0.f};

        for (int c = 0; c < NCH; ++c) {
            float4 st[2];
            if (c < NCH-1) {
                #pragma unroll
                for (int i = 0; i < 2; ++i) {
                    int off = i*512 + tid;
                    int r = off >> 3, k4 = off & 7;
                    st[i] = W4[(size_t)(v0 + r)*128 + (c+1)*8 + k4];
                }
            }
            const float4* wb = sm.wbuf[c & 1];
            #pragma unroll
            for (int c4 = 0; c4 < 8; ++c4) {
                const int c4g = c*8 + c4;
                float4 h0v = hT4[c4g*32 + b0];
                float4 h1v = hT4[c4g*32 + b0 + 1];
                #pragma unroll
                for (int i = 0; i < 4; ++i) {
                    float4 w = wb[(rslot*4 + i)*WROW + c4];
                    acc0[i] += w.x*h0v.x + w.y*h0v.y + w.z*h0v.z + w.w*h0v.w;
                    acc1[i] += w.x*h1v.x + w.y*h1v.y + w.z*h1v.z + w.w*h1v.w;
                }
            }
            if (c < NCH-1) {
                #pragma unroll
                for (int i = 0; i < 2; ++i) {
                    int off = i*512 + tid;
                    int r = off >> 3, k4 = off & 7;
                    sm.wbuf[(c+1) & 1][r*WROW + k4] = st[i];
                }
            }
            __syncthreads();
        }

        // epilogue: bias, store raw logits, per-thread softmax/argmax partials
        {
            const int vb = v0 + rslot*4;
            #pragma unroll
            for (int i = 0; i < 4; ++i) {
                float bb_ = bout[vb + i];
                acc0[i] += bb_; acc1[i] += bb_;
            }
            float* wpt = w_pro + (size_t)t*1024000;
            *(float4*)(wpt + (size_t)b0*VV + vb)     = make_float4(acc0[0], acc0[1], acc0[2], acc0[3]);
            *(float4*)(wpt + (size_t)(b0+1)*VV + vb) = make_float4(acc1[0], acc1[1], acc1[2], acc1[3]);

            float m0 = -INFINITY, s0 = 0.f, av0 = -INFINITY; int ai0 = 0;
            float m1 = -INFINITY, s1 = 0.f, av1 = -INFINITY; int ai1 = 0;
            #pragma unroll
            for (int i = 0; i < 4; ++i) {
                int v = vb + i;
                float val = acc0[i];
                if (val > m0) { s0 = s0*expf(m0 - val) + 1.f; m0 = val; }
                else          { s0 += expf(val - m0); }
                if (v >= 2 && val > av0) { av0 = val; ai0 = v; }
                float vl1 = acc1[i];
                if (vl1 > m1) { s1 = s1*expf(m1 - vl1) + 1.f; m1 = vl1; }
                else          { s1 += expf(vl1 - m1); }
                if (v >= 2 && vl1 > av1) { av1 = vl1; ai1 = v; }
            }
            sm.redSm[b0*32 + rslot]     = make_float4(m0, s0, av0, __int_as_float(ai0));
            sm.redSm[(b0+1)*32 + rslot] = make_float4(m1, s1, av1, __int_as_float(ai1));
        }
        __syncthreads();
        if (tid < 32) {
            float4 p0 = sm.redSm[tid*32];
            float m = p0.x, s = p0.y, av = p0.z; int ai = __float_as_int(p0.w);
            for (int j = 1; j < 32; ++j) {
                float4 p = sm.redSm[tid*32 + j];
                merge_sm(m, s, av, ai, p.x, p.y, p.z, __float_as_int(p.w));
            }
            part4[blk*32 + tid] = make_float4(m, s, av, __int_as_float(ai));
        }
        grid.sync();

        // ================= Phase RG =================
        {
            const int b = tid & 31, jg = tid >> 5;   // jg 0..15
            float m = -INFINITY, s = 0.f, av = -INFINITY; int ai = 0;
            #pragma unroll
            for (int i = 0; i < 16; ++i) {
                int j = jg + i*16;
                if (j < CNB) {
                    float4 p = part4[j*32 + b];
                    merge_sm(m, s, av, ai, p.x, p.y, p.z, __float_as_int(p.w));
                }
            }
            sm.redSm[tid] = make_float4(m, s, av, __int_as_float(ai));
        }
        __syncthreads();
        if (tid < 32) {
            float4 p0 = sm.redSm[tid];
            float m = p0.x, s = p0.y, av = p0.z; int ai = __float_as_int(p0.w);
            #pragma unroll
            for (int j = 1; j < 16; ++j) {
                float4 p = sm.redSm[tid + 32*j];
                merge_sm(m, s, av, ai, p.x, p.y, p.z, __float_as_int(p.w));
            }
            sm.mprev[tid] = m;
            sm.sprev[tid] = 1.f/s;
            sm.toksS[tid] = ai;
        }
        __syncthreads();
        const int oldflags = sm.flagsS;
        __syncthreads();
        {
            unsigned long long bal = __ballot((tid < 32) && (sm.toksS[tid & 31] == EOS_ID));
            if (tid == 0) sm.flagsS = oldflags | (int)(bal & 0xFFFFFFFFull);
        }
        if (blk < 32) {
            const int tok   = sm.toksS[blk];
            const int alive = ((oldflags >> blk) & 1) ^ 1;
            if (tid == 0) w_o[t*BB + blk] = alive ? (float)tok : 0.f;
            len_b += alive;
            if (tid < EE) {
                float e = alive ? emb[(size_t)tok*EE + tid] : 0.f;
                emb_sq[(size_t)t*8192 + blk*EE + tid] = e;
            }
            if (t == TT-1 && tid == 32) len_o[blk] = (float)len_b;
        }
        if (t < TT-1 && blk >= 64 && blk < 192)
            gru_phase(blk-64, tid, false, sm.toksS, emb, Wih, bih, Whh, bhh, h0,
                      (t & 1) ? hb1 : hb0, (t & 1) ? hb0 : hb1, gruS);
        grid.sync();
    }

    // ---- final normalize for t = 63
    {
        const int vl = tid & 127, bq = tid >> 7;
        float* wp = w_pro + (size_t)(TT-1)*1024000 + (size_t)blk*128;
        #pragma unroll
        for (int rr = 0; rr < 8; ++rr) {
            int b2 = rr*4 + bq;
            size_t idx = (size_t)b2*VV + vl;
            wp[idx] = expf(wp[idx] - sm.mprev[b2]) * sm.sprev[b2];
        }
    }
}

// ======================= fallback multi-launch path (round-2, proven) =======================
#define NBL 500
#define NT  256
#define WS_HT0   0
#define WS_HT1   16384
#define WS_X     32768
#define WS_PART  40960
#define WS_M     104960
#define WS_SINV  104992
#define WS_INT   105024

__global__ __launch_bounds__(NT)
void k_init(const float* __restrict__ emb, float* __restrict__ ws)
{
    float* xbuf = ws + WS_X;
    int* toki  = (int*)(ws + WS_INT);
    int* flags = toki;
    int* lenac = toki + 32;
    xbuf[blockIdx.x*EE + threadIdx.x] = emb[GO_ID*EE + threadIdx.x];
    if (blockIdx.x == 0 && threadIdx.x < BB) { flags[threadIdx.x] = 0; lenac[threadIdx.x] = 0; }
}

__global__ __launch_bounds__(NT)
void k_gru(const float* __restrict__ Wih, const float* __restrict__ bih,
           const float* __restrict__ Whh, const float* __restrict__ bhh,
           const float* __restrict__ h0, float* __restrict__ ws, int t)
{
    const int blk = blockIdx.x, tid = threadIdx.x;
    float* hTprev = ws + (((t & 1) == 0) ? WS_HT1 : WS_HT0);
    float* hTcur  = ws + (((t & 1) == 0) ? WS_HT0 : WS_HT1);
    const float* xbuf = ws + WS_X;

    __shared__ float smem[1536];

    const int b    = tid & 31;
    const int q    = tid >> 5;
    const int k    = blk*4 + (q & 3);
    const int half = q >> 2;

    float s_ir = 0.f, s_iz = 0.f, s_in = 0.f;
    {
        const float4* x4 = (const float4*)xbuf + b*64;
        const float4* wr = (const float4*)Wih + (size_t)k*64;
        const float4* wz = (const float4*)Wih + (size_t)(HH + k)*64;
        const float4* wn = (const float4*)Wih + (size_t)(2*HH + k)*64;
        const int c0 = half*32, c1 = c0 + 32;
        for (int c4 = c0; c4 < c1; ++c4) {
            float4 xv = x4[c4];
            float4 a  = wr[c4]; s_ir += a.x*xv.x + a.y*xv.y + a.z*xv.z + a.w*xv.w;
            float4 bz = wz[c4]; s_iz += bz.x*xv.x + bz.y*xv.y + bz.z*xv.z + bz.w*xv.w;
            float4 cn = wn[c4]; s_in += cn.x*xv.x + cn.y*xv.y + cn.z*xv.z + cn.w*xv.w;
        }
    }
    float s_hr = 0.f, s_hz = 0.f, s_hn = 0.f;
    {
        const float4* wr = (const float4*)Whh + (size_t)k*128;
        const float4* wz = (const float4*)Whh + (size_t)(HH + k)*128;
        const float4* wn = (const float4*)Whh + (size_t)(2*HH + k)*128;
        const int c0 = half*64, c1 = c0 + 64;
        if (t == 0) {
            const float4* h4 = (const float4*)h0 + b*128;
            for (int c4 = c0; c4 < c1; ++c4) {
                float4 hv = h4[c4];
                float4 a  = wr[c4]; s_hr += a.x*hv.x + a.y*hv.y + a.z*hv.z + a.w*hv.w;
                float4 bz = wz[c4]; s_hz += bz.x*hv.x + bz.y*hv.y + bz.z*hv.z + bz.w*hv.w;
                float4 cn = wn[c4]; s_hn += cn.x*hv.x + cn.y*hv.y + cn.z*hv.z + cn.w*hv.w;
            }
        } else {
            const float4* h4 = (const float4*)hTprev;
            for (int c4 = c0; c4 < c1; ++c4) {
                float4 hv = h4[c4*32 + b];
                float4 a  = wr[c4]; s_hr += a.x*hv.x + a.y*hv.y + a.z*hv.z + a.w*hv.w;
                float4 bz = wz[c4]; s_hz += bz.x*hv.x + bz.y*hv.y + bz.z*hv.z + bz.w*hv.w;
                float4 cn = wn[c4]; s_hn += cn.x*hv.x + cn.y*hv.y + cn.z*hv.z + cn.w*hv.w;
            }
        }
    }
    const int si = (q*32 + b)*6;
    smem[si+0] = s_ir; smem[si+1] = s_iz; smem[si+2] = s_in;
    smem[si+3] = s_hr; smem[si+4] = s_hz; smem[si+5] = s_hn;
    __syncthreads();
    if (q < 4) {
        const int i0 = (q*32 + b)*6, i1 = ((q+4)*32 + b)*6;
        float ir  = smem[i0+0] + smem[i1+0] + bih[k];
        float iz  = smem[i0+1] + smem[i1+1] + bih[HH + k];
        float inn = smem[i0+2] + smem[i1+2] + bih[2*HH + k];
        float hr  = smem[i0+3] + smem[i1+3] + bhh[k];
        float hz  = smem[i0+4] + smem[i1+4] + bhh[HH + k];
        float hn  = smem[i0+5] + smem[i1+5] + bhh[2*HH + k];
        float r = 1.f/(1.f + expf(-(ir + hr)));
        float z = 1.f/(1.f + expf(-(iz + hz)));
        float n = tanhf(inn + r*hn);
        float hp = (t == 0) ? h0[b*HH + k] : hTprev[(k>>2)*128 + b*4 + (k&3)];
        float hv = (1.f - z)*n + z*hp;
        hTcur[(k>>2)*128 + b*4 + (k&3)] = hv;
    }
}

__global__ __launch_bounds__(NT)
void k_logits(const float* __restrict__ Wout, const float* __restrict__ bout,
              float* __restrict__ out, float* __restrict__ ws, int t)
{
    const int blk = blockIdx.x, tid = threadIdx.x;
    const float* hTcur = ws + (((t & 1) == 0) ? WS_HT0 : WS_HT1);
    float* part  = ws + WS_PART;
    const float* Mrow  = ws + WS_M;
    const float* SinvA = ws + WS_SINV;
    float* w_pro = out;

    __shared__ float smem[2080];

    if (t > 0) {
        float* wp = w_pro + (size_t)(t-1)*1024000 + blk*64;
        const int vl = tid & 63, bq = tid >> 6;
        #pragma unroll
        for (int r = 0; r < 8; ++r) {
            int b = r*4 + bq;
            size_t idx = (size_t)b*VV + vl;
            wp[idx] = expf(wp[idx] - Mrow[b]) * SinvA[b];
        }
    }

    const int b  = tid & 31;
    const int vg = tid >> 5;
    const int v0 = blk*64 + vg*8;
    float acc[8] = {0.f,0.f,0.f,0.f,0.f,0.f,0.f,0.f};
    const float4* hT4  = (const float4*)hTcur;
    const float4* wrow = (const float4*)Wout + (size_t)v0*128;
    for (int c4 = 0; c4 < 128; ++c4) {
        float4 hv = hT4[c4*32 + b];
        #pragma unroll
        for (int i = 0; i < 8; ++i) {
            float4 wv = wrow[(size_t)i*128 + c4];
            acc[i] += wv.x*hv.x + wv.y*hv.y + wv.z*hv.z + wv.w*hv.w;
        }
    }
    __syncthreads();
    #pragma unroll
    for (int i = 0; i < 8; ++i)
        smem[b*65 + vg*8 + i] = acc[i] + bout[v0 + i];
    __syncthreads();
    {
        float* wp = w_pro + (size_t)t*1024000 + blk*64;
        const int vl = tid & 63, bq = tid >> 6;
        #pragma unroll
        for (int r = 0; r < 8; ++r) {
            int b2 = r*4 + bq;
            wp[(size_t)b2*VV + vl] = smem[b2*65 + vl];
        }
    }
    {
        const int rb = tid >> 3, l = tid & 7;
        float m = -INFINITY, s = 0.f, av = -INFINITY; int ai = 0;
        for (int j = l; j < 64; j += 8) {
            float val = smem[rb*65 + j];
            if (val > m) { s = s*expf(m - val) + 1.f; m = val; }
            else         { s += expf(val - m); }
            int vglob = blk*64 + j;
            if (vglob >= 2 && val > av) { av = val; ai = vglob; }
        }
        for (int d = 1; d < 8; d <<= 1) {
            float m2  = __shfl_xor(m, d);
            float s2  = __shfl_xor(s, d);
            float av2 = __shfl_xor(av, d);
            int   ai2 = __shfl_xor(ai, d);
            float mn = fmaxf(m, m2);
            s = s*expf(m - mn) + s2*expf(m2 - mn); m = mn;
            if (av2 > av || (av2 == av && ai2 < ai)) { av = av2; ai = ai2; }
        }
        if (l == 0)
            ((float4*)part)[blk*32 + rb] = make_float4(m, s, av, __int_as_float(ai));
    }
}

__global__ __launch_bounds__(NT)
void k_reduce(const float* __restrict__ emb, float* __restrict__ out,
              float* __restrict__ ws, int t)
{
    const int b = blockIdx.x, tid = threadIdx.x;
    const float* part = ws + WS_PART;
    float* Mrow  = ws + WS_M;
    float* SinvA = ws + WS_SINV;
    int*   flags = (int*)(ws + WS_INT);
    int*   lenac = flags + 32;
    float* xbuf  = ws + WS_X;

    float* w_o    = out + OUT_WO;
    float* emb_sq = out + OUT_EMB;
    float* len_o  = out + OUT_LEN;

    __shared__ float smem[32];

    float m = -INFINITY, s = 0.f, av = -INFINITY; int ai = 0;
    for (int j = tid; j < NBL; j += NT) {
        float4 p = ((const float4*)part)[j*32 + b];
        float mn = fmaxf(m, p.x);
        s = s*expf(m - mn) + p.y*expf(p.x - mn); m = mn;
        int aij = __float_as_int(p.w);
        if (p.z > av || (p.z == av && aij < ai)) { av = p.z; ai = aij; }
    }
    for (int d = 1; d < 64; d <<= 1) {
        float m2  = __shfl_xor(m, d);
        float s2  = __shfl_xor(s, d);
        float av2 = __shfl_xor(av, d);
        int   ai2 = __shfl_xor(ai, d);
        float mn = fmaxf(m, m2);
        s = s*expf(m - mn) + s2*expf(m2 - mn); m = mn;
        if (av2 > av || (av2 == av && ai2 < ai)) { av = av2; ai = ai2; }
    }
    const int wid = tid >> 6, lane = tid & 63;
    if (lane == 0) {
        smem[wid*4+0] = m; smem[wid*4+1] = s;
        smem[wid*4+2] = av; smem[wid*4+3] = __int_as_float(ai);
    }
    __syncthreads();
    if (tid == 0) {
        float M = smem[0], S = smem[1], AV = smem[2];
        int AI = __float_as_int(smem[3]);
        for (int w2 = 1; w2 < 4; ++w2) {
            float m2 = smem[w2*4], s2 = smem[w2*4+1], av2 = smem[w2*4+2];
            int ai2 = __float_as_int(smem[w2*4+3]);
            float mn = fmaxf(M, m2);
            S = S*expf(M - mn) + s2*expf(m2 - mn); M = mn;
            if (av2 > AV || (av2 == AV && ai2 < AI)) { AV = av2; AI = ai2; }
        }
        Mrow[b] = M; SinvA[b] = 1.f/S;
        int fl = flags[b];
        int alive = fl ? 0 : 1;
        w_o[t*BB + b] = alive ? (float)AI : 0.f;
        flags[b] = fl | (AI == EOS_ID ? 1 : 0);
        lenac[b] += alive;
        if (t == TT-1) len_o[b] = (float)lenac[b];
        smem[16] = __int_as_float(AI);
        smem[17] = (float)alive;
    }
    __syncthreads();
    const int tok = __float_as_int(smem[16]);
    const float alive = smem[17];
    float e = emb[(size_t)tok*EE + tid];
    xbuf[b*EE + tid] = e;
    emb_sq[(size_t)t*8192 + b*EE + tid] = alive * e;
}

__global__ __launch_bounds__(NT)
void k_norm_last(float* __restrict__ out, float* __restrict__ ws)
{
    const int blk = blockIdx.x, tid = threadIdx.x;
    const float* Mrow  = ws + WS_M;
    const float* SinvA = ws + WS_SINV;
    float* wp = out + (size_t)(TT-1)*1024000 + blk*64;
    const int vl = tid & 63, bq = tid >> 6;
    #pragma unroll
    for (int r = 0; r < 8; ++r) {
        int b = r*4 + bq;
        size_t idx = (size_t)b*VV + vl;
        wp[idx] = expf(wp[idx] - Mrow[b]) * SinvA[b];
    }
}

extern "C" void kernel_launch(void* const* d_in, const int* in_sizes, int n_in,
                              void* d_out, int out_size, void* d_ws, size_t ws_size,
                              hipStream_t stream)
{
    const float* emb  = (const float*)d_in[0];
    const float* Wih  = (const float*)d_in[1];
    const float* bih  = (const float*)d_in[2];
    const float* Whh  = (const float*)d_in[3];
    const float* bhh  = (const float*)d_in[4];
    const float* Wout = (const float*)d_in[5];
    const float* bout = (const float*)d_in[6];
    const float* h0   = (const float*)d_in[7];
    float* out = (float*)d_out;
    float* ws  = (float*)d_ws;

    void* args[] = { (void*)&emb, (void*)&Wih, (void*)&bih, (void*)&Whh, (void*)&bhh,
                     (void*)&Wout, (void*)&bout, (void*)&h0, (void*)&out, (void*)&ws };
    hipError_t err = hipLaunchCooperativeKernel((const void*)fused_decoder,
                                                dim3(CNB), dim3(CNT), args, 0, stream);
    if (err != hipSuccess) {
        (void)hipGetLastError();   // clear sticky error; use proven multi-launch path
        hipLaunchKernelGGL(k_init, dim3(BB), dim3(NT), 0, stream, emb, ws);
        for (int t = 0; t < TT; ++t) {
            hipLaunchKernelGGL(k_gru,    dim3(128), dim3(NT), 0, stream, Wih, bih, Whh, bhh, h0, ws, t);
            hipLaunchKernelGGL(k_logits, dim3(NBL), dim3(NT), 0, stream, Wout, bout, out, ws, t);
            hipLaunchKernelGGL(k_reduce, dim3(BB),  dim3(NT), 0, stream, emb, out, ws, t);
        }
        hipLaunchKernelGGL(k_norm_last, dim3(NBL), dim3(NT), 0, stream, out, ws);
    }
}